// Round 1
// baseline (957.562 us; speedup 1.0000x reference)
//
#include <hip/hip_runtime.h>
#include <math.h>

// Problem constants (from reference)
constexpr int cN0  = 260000;
constexpr int cN1  = 10240;
constexpr int cB   = 1024;
constexpr int cE0  = 256000;
constexpr int cE1  = 10240;
constexpr int cIN  = 602;   // IN_C
constexpr int cHID = 256;
constexpr int cOUT = 41;
constexpr int KP   = 608;   // cIN padded up to multiple of 16 (float4-aligned rows)

__device__ __forceinline__ int lower_bound_dev(const int* __restrict__ a, int n, int v) {
    int l = 0, r = n;
    while (l < r) { int m = (l + r) >> 1; if (a[m] < v) l = m + 1; else r = m; }
    return l;
}

// ---------------------------------------------------------------------------
// Kernel 1: layer-0 mean aggregation (block per target, channel per thread).
// dst0 is sorted -> per-target contiguous edge range via binary search.
// Also copies x[:N1] into a KP-padded buffer (xpad) for aligned GEMM loads.
// ---------------------------------------------------------------------------
__global__ __launch_bounds__(256) void k_agg0(
    const float* __restrict__ x, const int* __restrict__ src0,
    const int* __restrict__ dst0, float* __restrict__ agg0,
    float* __restrict__ xpad)
{
    const int t   = blockIdx.x;      // target node in [0, N1)
    const int tid = threadIdx.x;
    const int lo  = lower_bound_dev(dst0, cE0, t);
    const int hi  = lower_bound_dev(dst0, cE0, t + 1);
    const int cnt = hi - lo;

    float a0 = 0.f, a1 = 0.f, a2 = 0.f;
    __shared__ int s_src[256];
    for (int base = lo; base < hi; base += 256) {
        const int n = min(256, hi - base);
        __syncthreads();
        if (tid < n) s_src[tid] = src0[base + tid];
        __syncthreads();
        for (int j = 0; j < n; ++j) {
            const float* row = x + (long)s_src[j] * cIN;
            a0 += row[tid];
            a1 += row[tid + 256];
            if (tid < cIN - 512) a2 += row[tid + 512];
        }
    }

    const float inv = 1.f / (float)(cnt > 1 ? cnt : 1);
    float*       og = agg0 + (long)t * KP;
    float*       ox = xpad + (long)t * KP;
    const float* xr = x    + (long)t * cIN;

    og[tid]       = a0 * inv;   ox[tid]       = xr[tid];
    og[tid + 256] = a1 * inv;   ox[tid + 256] = xr[tid + 256];
    if (tid < cIN - 512) {              // channels 512..601
        og[tid + 512] = a2 * inv;
        ox[tid + 512] = xr[tid + 512];
    } else if (tid < KP - 512) {        // pad channels 602..607 -> 0
        og[tid + 512] = 0.f;
        ox[tid + 512] = 0.f;
    }
}

// ---------------------------------------------------------------------------
// Kernel 2: h = relu(agg0 @ W_l0 + b_l0 + x_tgt @ W_r0)
// Virtual-concat GEMM: two K-phases of KP=608 each (zero-padded A cols,
// bounds-checked W rows). 64x64 tile, 4x4 micro-tile, 256 threads.
// ---------------------------------------------------------------------------
__global__ __launch_bounds__(256) void k_gemm1(
    const float* __restrict__ agg0, const float* __restrict__ xpad,
    const float* __restrict__ Wl,   const float* __restrict__ Wr,
    const float* __restrict__ bias, float* __restrict__ h)
{
    const int tid = threadIdx.x;
    const int n0  = (blockIdx.x & 3) * 64;
    const int m0  = (blockIdx.x >> 2) * 64;

    __shared__ float As[16][68];   // [k][m], +4 pad keeps float4 alignment
    __shared__ float Bs[16][68];   // [k][n]

    float acc[4][4] = {};
    const int tx = tid & 15, ty = tid >> 4;          // micro-tile coords
    const int ai = tid >> 2, ak = (tid & 3) * 4;     // A loader: row ai, k-quad ak
    const int bk = tid >> 4, bj = (tid & 15) * 4;    // B loader: k bk, col-quad bj

    for (int phase = 0; phase < 2; ++phase) {
        const float* A = phase ? xpad : agg0;
        const float* W = phase ? Wr   : Wl;
        for (int k0 = 0; k0 < KP; k0 += 16) {
            __syncthreads();
            const float4 av = *(const float4*)(A + (long)(m0 + ai) * KP + k0 + ak);
            As[ak + 0][ai] = av.x;
            As[ak + 1][ai] = av.y;
            As[ak + 2][ai] = av.z;
            As[ak + 3][ai] = av.w;
            const int kg = k0 + bk;
            float4 bv = make_float4(0.f, 0.f, 0.f, 0.f);
            if (kg < cIN) bv = *(const float4*)(W + (long)kg * cHID + n0 + bj);
            Bs[bk][bj + 0] = bv.x;
            Bs[bk][bj + 1] = bv.y;
            Bs[bk][bj + 2] = bv.z;
            Bs[bk][bj + 3] = bv.w;
            __syncthreads();
            #pragma unroll
            for (int kk = 0; kk < 16; ++kk) {
                const float4 a4 = *(const float4*)&As[kk][ty * 4];
                const float4 b4 = *(const float4*)&Bs[kk][tx * 4];
                acc[0][0] += a4.x * b4.x; acc[0][1] += a4.x * b4.y;
                acc[0][2] += a4.x * b4.z; acc[0][3] += a4.x * b4.w;
                acc[1][0] += a4.y * b4.x; acc[1][1] += a4.y * b4.y;
                acc[1][2] += a4.y * b4.z; acc[1][3] += a4.y * b4.w;
                acc[2][0] += a4.z * b4.x; acc[2][1] += a4.z * b4.y;
                acc[2][2] += a4.z * b4.z; acc[2][3] += a4.z * b4.w;
                acc[3][0] += a4.w * b4.x; acc[3][1] += a4.w * b4.y;
                acc[3][2] += a4.w * b4.z; acc[3][3] += a4.w * b4.w;
            }
        }
    }

    #pragma unroll
    for (int i = 0; i < 4; ++i) {
        const int m = m0 + ty * 4 + i;
        float4 o;
        o.x = fmaxf(acc[i][0] + bias[n0 + tx * 4 + 0], 0.f);
        o.y = fmaxf(acc[i][1] + bias[n0 + tx * 4 + 1], 0.f);
        o.z = fmaxf(acc[i][2] + bias[n0 + tx * 4 + 2], 0.f);
        o.w = fmaxf(acc[i][3] + bias[n0 + tx * 4 + 3], 0.f);
        *(float4*)(h + (long)m * cHID + n0 + tx * 4) = o;
    }
}

// ---------------------------------------------------------------------------
// Kernel 3: layer-1 mean aggregation (block per target, 256 ch = 256 threads)
// ---------------------------------------------------------------------------
__global__ __launch_bounds__(256) void k_agg1(
    const float* __restrict__ h, const int* __restrict__ src1,
    const int* __restrict__ dst1, float* __restrict__ agg1)
{
    const int t   = blockIdx.x;
    const int tid = threadIdx.x;
    const int lo  = lower_bound_dev(dst1, cE1, t);
    const int hi  = lower_bound_dev(dst1, cE1, t + 1);
    const int cnt = hi - lo;

    float a = 0.f;
    __shared__ int s_src[256];
    for (int base = lo; base < hi; base += 256) {
        const int n = min(256, hi - base);
        __syncthreads();
        if (tid < n) s_src[tid] = src1[base + tid];
        __syncthreads();
        for (int j = 0; j < n; ++j) a += h[(long)s_src[j] * cHID + tid];
    }
    agg1[(long)t * cHID + tid] = a / (float)(cnt > 1 ? cnt : 1);
}

// ---------------------------------------------------------------------------
// Kernel 4: out = log_softmax(agg1 @ W_l1 + b_l1 + h[:B] @ W_r1)
// One wave per row; 41 logits in 41 lanes; shuffle reductions (wave=64).
// ---------------------------------------------------------------------------
__global__ __launch_bounds__(64) void k_out(
    const float* __restrict__ h,  const float* __restrict__ agg1,
    const float* __restrict__ Wl, const float* __restrict__ bias,
    const float* __restrict__ Wr, float* __restrict__ out)
{
    const int row = blockIdx.x;
    const int tid = threadIdx.x;
    __shared__ float sA[cHID], sH[cHID];
    for (int i = tid; i < cHID; i += 64) {
        sA[i] = agg1[(long)row * cHID + i];
        sH[i] = h[(long)row * cHID + i];
    }
    __syncthreads();

    float v = 0.f;
    if (tid < cOUT) {
        v = bias[tid];
        for (int k = 0; k < cHID; ++k)
            v += sA[k] * Wl[k * cOUT + tid] + sH[k] * Wr[k * cOUT + tid];
    }
    float lg = (tid < cOUT) ? v : -INFINITY;
    float m = lg;
    #pragma unroll
    for (int off = 32; off > 0; off >>= 1) m = fmaxf(m, __shfl_down(m, off));
    m = __shfl(m, 0);
    float e = (tid < cOUT) ? expf(v - m) : 0.f;
    float s = e;
    #pragma unroll
    for (int off = 32; off > 0; off >>= 1) s += __shfl_down(s, off);
    s = __shfl(s, 0);
    if (tid < cOUT) out[(long)row * cOUT + tid] = v - m - logf(s);
}

// ---------------------------------------------------------------------------
extern "C" void kernel_launch(void* const* d_in, const int* in_sizes, int n_in,
                              void* d_out, int out_size, void* d_ws, size_t ws_size,
                              hipStream_t stream)
{
    const float* x    = (const float*)d_in[0];
    const float* Wl0  = (const float*)d_in[1];
    const float* bl0  = (const float*)d_in[2];
    const float* Wr0  = (const float*)d_in[3];
    const float* Wl1  = (const float*)d_in[4];
    const float* bl1  = (const float*)d_in[5];
    const float* Wr1  = (const float*)d_in[6];
    const int*   src0 = (const int*)d_in[7];
    const int*   dst0 = (const int*)d_in[8];
    const int*   src1 = (const int*)d_in[9];
    const int*   dst1 = (const int*)d_in[10];
    float* out = (float*)d_out;

    // Workspace layout (bytes):
    //   agg0: N1*KP*4 = 24.9 MB   @ 0
    //   xpad: N1*KP*4 = 24.9 MB   @ 24.9 MB
    //   h:    N1*256*4 = 10.5 MB  @ 49.8 MB
    //   agg1: B*256*4  = 1.05 MB  @ 60.3 MB
    char* ws = (char*)d_ws;
    const size_t szPad = (size_t)cN1 * KP * sizeof(float);
    float* agg0 = (float*)(ws);
    float* xpad = (float*)(ws + szPad);
    float* h    = (float*)(ws + 2 * szPad);
    float* agg1 = (float*)(ws + 2 * szPad + (size_t)cN1 * cHID * sizeof(float));

    k_agg0<<<cN1, 256, 0, stream>>>(x, src0, dst0, agg0, xpad);
    k_gemm1<<<(cN1 / 64) * 4, 256, 0, stream>>>(agg0, xpad, Wl0, Wr0, bl0, h);
    k_agg1<<<cB, 256, 0, stream>>>(h, src1, dst1, agg1);
    k_out<<<cB, 64, 0, stream>>>(h, agg1, Wl1, bl1, Wr1, out);
}

// Round 2
// 871.019 us; speedup vs baseline: 1.0994x; 1.0994x over previous
//
#include <hip/hip_runtime.h>
#include <hip/hip_bf16.h>
#include <math.h>

// Problem constants (from reference)
constexpr int cN1  = 10240;
constexpr int cB   = 1024;
constexpr int cE0  = 256000;
constexpr int cE1  = 10240;
constexpr int cIN  = 602;   // IN_C
constexpr int cHID = 256;
constexpr int cOUT = 41;
constexpr int KC   = 1216;  // virtual-concat K: [agg(602) pad->608 | x_tgt(602) pad->608]

typedef __attribute__((ext_vector_type(8))) short short8;  // 8 bf16 (4 VGPRs)
typedef __attribute__((ext_vector_type(4))) float f32x4;   // MFMA 16x16 C/D

__device__ __forceinline__ int lower_bound_dev(const int* __restrict__ a, int n, int v) {
    int l = 0, r = n;
    while (l < r) { int m = (l + r) >> 1; if (a[m] < v) l = m + 1; else r = m; }
    return l;
}

// ---------------------------------------------------------------------------
// Kernel 1: layer-0 mean aggregation; writes bf16 concat buffer
//   cat[t][0..601]    = mean_{e: dst0[e]==t} x[src0[e]]   (cols 602..607 = 0)
//   cat[t][608..1209] = x[t]                              (cols 1210..1215 = 0)
// Block per target (dst0 sorted -> contiguous edge range), channel per thread.
// ---------------------------------------------------------------------------
__global__ __launch_bounds__(256) void k_agg0(
    const float* __restrict__ x, const int* __restrict__ src0,
    const int* __restrict__ dst0, __hip_bfloat16* __restrict__ cat)
{
    const int t   = blockIdx.x;
    const int tid = threadIdx.x;
    const int lo  = lower_bound_dev(dst0, cE0, t);
    const int hi  = lower_bound_dev(dst0, cE0, t + 1);
    const int cnt = hi - lo;

    float a0 = 0.f, a1 = 0.f, a2 = 0.f;
    __shared__ int s_src[256];
    for (int base = lo; base < hi; base += 256) {
        const int n = min(256, hi - base);
        __syncthreads();
        if (tid < n) s_src[tid] = src0[base + tid];
        __syncthreads();
        for (int j = 0; j < n; ++j) {
            const float* row = x + (long)s_src[j] * cIN;
            a0 += row[tid];
            a1 += row[tid + 256];
            if (tid < cIN - 512) a2 += row[tid + 512];
        }
    }

    const float inv = 1.f / (float)(cnt > 1 ? cnt : 1);
    __hip_bfloat16* cr = cat + (long)t * KC;
    const float*    xr = x   + (long)t * cIN;

    cr[tid]             = __float2bfloat16(a0 * inv);
    cr[tid + 256]       = __float2bfloat16(a1 * inv);
    cr[608 + tid]       = __float2bfloat16(xr[tid]);
    cr[608 + 256 + tid] = __float2bfloat16(xr[tid + 256]);
    if (tid < 96) {  // cols 512..607 of each half: 90 real channels + 6 pad
        const float va = (tid < 90) ? a2 * inv      : 0.f;
        const float vx = (tid < 90) ? xr[512 + tid] : 0.f;
        cr[512 + tid]       = __float2bfloat16(va);
        cr[608 + 512 + tid] = __float2bfloat16(vx);
    }
}

// ---------------------------------------------------------------------------
// Kernel 2: build transposed bf16 weights Wt[n][k], n in [0,256), k in [0,1216)
//   k<602 -> W_l0[k][n]; 608<=k<1210 -> W_r0[k-608][n]; else 0
// ---------------------------------------------------------------------------
__global__ __launch_bounds__(256) void k_prep_w(
    const float* __restrict__ Wl, const float* __restrict__ Wr,
    __hip_bfloat16* __restrict__ Wt)
{
    const int idx = blockIdx.x * 256 + threadIdx.x;   // n*KC + k, grid = 256*1216/256
    const int n = idx / KC, k = idx - n * KC;
    float v = 0.f;
    if (k < cIN)                        v = Wl[(long)k * cHID + n];
    else if (k >= 608 && k < 608 + cIN) v = Wr[(long)(k - 608) * cHID + n];
    Wt[idx] = __float2bfloat16(v);
}

// ---------------------------------------------------------------------------
// Kernel 3: h = relu(cat @ Wt^T + bias)   [10240 x 256], bf16 MFMA.
// 64x64 block tile, 4 waves x (32x32 = 2x2 fragments of 16x16x32).
// LDS: As[m][k], Bs[n][k] (both k-contiguous -> ds_read_b128 fragments).
// Fragment layouts (m89-verified): A: m=lane&15, k=quad*8+j;
// B: n=lane&15, k=quad*8+j; D: col=lane&15, row=quad*4+reg.
// ---------------------------------------------------------------------------
__global__ __launch_bounds__(256) void k_gemm(
    const __hip_bfloat16* __restrict__ cat, const __hip_bfloat16* __restrict__ Wt,
    const float* __restrict__ bias, float* __restrict__ h)
{
    const int tid  = threadIdx.x;
    const int m0   = (blockIdx.x >> 2) * 64;
    const int n0   = (blockIdx.x & 3) * 64;
    const int w    = tid >> 6, lane = tid & 63;
    const int wm   = (w & 1) * 32, wn = (w >> 1) * 32;
    const int lrow = lane & 15, quad = lane >> 4;

    __shared__ __hip_bfloat16 As[64 * 32];
    __shared__ __hip_bfloat16 Bs[64 * 32];

    f32x4 acc[2][2] = {};

    // staging: thread loads 16 B of A and 16 B of B per K-step
    const int srow = tid >> 2, schunk = tid & 3;
    const __hip_bfloat16* gA = cat + (long)(m0 + srow) * KC + schunk * 8;
    const __hip_bfloat16* gB = Wt  + (long)(n0 + srow) * KC + schunk * 8;
    __hip_bfloat16* lA = As + srow * 32 + schunk * 8;
    __hip_bfloat16* lB = Bs + srow * 32 + schunk * 8;

    for (int k0 = 0; k0 < KC; k0 += 32) {
        const short8 av = *(const short8*)(gA + k0);
        const short8 bv = *(const short8*)(gB + k0);
        __syncthreads();
        *(short8*)lA = av;
        *(short8*)lB = bv;
        __syncthreads();

        short8 af[2], bf[2];
        #pragma unroll
        for (int f = 0; f < 2; ++f) {
            af[f] = *(const short8*)(As + (wm + f * 16 + lrow) * 32 + quad * 8);
            bf[f] = *(const short8*)(Bs + (wn + f * 16 + lrow) * 32 + quad * 8);
        }
        #pragma unroll
        for (int fm = 0; fm < 2; ++fm)
            #pragma unroll
            for (int fn = 0; fn < 2; ++fn)
                acc[fm][fn] = __builtin_amdgcn_mfma_f32_16x16x32_bf16(
                    af[fm], bf[fn], acc[fm][fn], 0, 0, 0);
    }

    #pragma unroll
    for (int fm = 0; fm < 2; ++fm)
        #pragma unroll
        for (int fn = 0; fn < 2; ++fn) {
            const int col = n0 + wn + fn * 16 + lrow;
            const float b = bias[col];
            #pragma unroll
            for (int r = 0; r < 4; ++r) {
                const int row = m0 + wm + fm * 16 + quad * 4 + r;
                h[(long)row * cHID + col] = fmaxf(acc[fm][fn][r] + b, 0.f);
            }
        }
}

// ---------------------------------------------------------------------------
// Kernel 4: layer-1 mean aggregation (fp32, small)
// ---------------------------------------------------------------------------
__global__ __launch_bounds__(256) void k_agg1(
    const float* __restrict__ h, const int* __restrict__ src1,
    const int* __restrict__ dst1, float* __restrict__ agg1)
{
    const int t   = blockIdx.x;
    const int tid = threadIdx.x;
    const int lo  = lower_bound_dev(dst1, cE1, t);
    const int hi  = lower_bound_dev(dst1, cE1, t + 1);
    const int cnt = hi - lo;

    float a = 0.f;
    __shared__ int s_src[256];
    for (int base = lo; base < hi; base += 256) {
        const int n = min(256, hi - base);
        __syncthreads();
        if (tid < n) s_src[tid] = src1[base + tid];
        __syncthreads();
        for (int j = 0; j < n; ++j) a += h[(long)s_src[j] * cHID + tid];
    }
    agg1[(long)t * cHID + tid] = a / (float)(cnt > 1 ? cnt : 1);
}

// ---------------------------------------------------------------------------
// Kernel 5: out = log_softmax(agg1 @ W_l1 + b_l1 + h[:B] @ W_r1)  (fp32)
// ---------------------------------------------------------------------------
__global__ __launch_bounds__(64) void k_out(
    const float* __restrict__ h,  const float* __restrict__ agg1,
    const float* __restrict__ Wl, const float* __restrict__ bias,
    const float* __restrict__ Wr, float* __restrict__ out)
{
    const int row = blockIdx.x;
    const int tid = threadIdx.x;
    __shared__ float sA[cHID], sH[cHID];
    for (int i = tid; i < cHID; i += 64) {
        sA[i] = agg1[(long)row * cHID + i];
        sH[i] = h[(long)row * cHID + i];
    }
    __syncthreads();

    float v = 0.f;
    if (tid < cOUT) {
        v = bias[tid];
        for (int k = 0; k < cHID; ++k)
            v += sA[k] * Wl[k * cOUT + tid] + sH[k] * Wr[k * cOUT + tid];
    }
    float lg = (tid < cOUT) ? v : -INFINITY;
    float m = lg;
    #pragma unroll
    for (int off = 32; off > 0; off >>= 1) m = fmaxf(m, __shfl_down(m, off));
    m = __shfl(m, 0);
    float e = (tid < cOUT) ? expf(v - m) : 0.f;
    float s = e;
    #pragma unroll
    for (int off = 32; off > 0; off >>= 1) s += __shfl_down(s, off);
    s = __shfl(s, 0);
    if (tid < cOUT) out[(long)row * cOUT + tid] = v - m - logf(s);
}

// ---------------------------------------------------------------------------
extern "C" void kernel_launch(void* const* d_in, const int* in_sizes, int n_in,
                              void* d_out, int out_size, void* d_ws, size_t ws_size,
                              hipStream_t stream)
{
    const float* x    = (const float*)d_in[0];
    const float* Wl0  = (const float*)d_in[1];
    const float* bl0  = (const float*)d_in[2];
    const float* Wr0  = (const float*)d_in[3];
    const float* Wl1  = (const float*)d_in[4];
    const float* bl1  = (const float*)d_in[5];
    const float* Wr1  = (const float*)d_in[6];
    const int*   src0 = (const int*)d_in[7];
    const int*   dst0 = (const int*)d_in[8];
    const int*   src1 = (const int*)d_in[9];
    const int*   dst1 = (const int*)d_in[10];
    float* out = (float*)d_out;

    // Workspace layout (bytes, 256-aligned):
    //   cat : N1*KC*2   = 24.90 MB
    //   Wt  : 256*KC*2  =  0.62 MB
    //   h   : N1*256*4  = 10.49 MB
    //   agg1: B*256*4   =  1.05 MB
    char* ws = (char*)d_ws;
    const size_t szCat = (size_t)cN1 * KC * sizeof(__hip_bfloat16);
    const size_t szWt  = (size_t)cHID * KC * sizeof(__hip_bfloat16);
    const size_t szH   = (size_t)cN1 * cHID * sizeof(float);
    __hip_bfloat16* cat  = (__hip_bfloat16*)(ws);
    __hip_bfloat16* Wt   = (__hip_bfloat16*)(ws + szCat);
    float*          h    = (float*)(ws + szCat + szWt);
    float*          agg1 = (float*)(ws + szCat + szWt + szH);

    k_prep_w<<<(cHID * KC) / 256, 256, 0, stream>>>(Wl0, Wr0, Wt);
    k_agg0<<<cN1, 256, 0, stream>>>(x, src0, dst0, cat);
    k_gemm<<<(cN1 / 64) * 4, 256, 0, stream>>>(cat, Wt, bl0, h);
    k_agg1<<<cB, 256, 0, stream>>>(h, src1, dst1, agg1);
    k_out<<<cB, 64, 0, stream>>>(h, agg1, Wl1, bl1, Wr1, out);
}